// Round 12
// baseline (233.044 us; speedup 1.0000x reference)
//
#include <hip/hip_runtime.h>

typedef _Float16 f16x8 __attribute__((ext_vector_type(8)));
typedef __fp16 fp16v2 __attribute__((ext_vector_type(2)));
typedef _Float16 f16v2 __attribute__((ext_vector_type(2)));
typedef short short8 __attribute__((ext_vector_type(8)));
typedef float f32x16 __attribute__((ext_vector_type(16)));

#define DD 512
#define NG 512

typedef __attribute__((address_space(3))) void lds_void;
typedef __attribute__((address_space(1))) void glb_void;

static __device__ __forceinline__ void gload_lds16(const void* g, void* l) {
  __builtin_amdgcn_global_load_lds((const glb_void*)g, (lds_void*)l, 16, 0, 0);
}

#define WAITV(n) asm volatile("s_waitcnt vmcnt(" #n ")" ::: "memory")
#define MEMFENCE asm volatile("" ::: "memory")

// packed f32x2 -> f16x2 (RTZ), bit-cast to _Float16 vector
static __device__ __forceinline__ f16v2 pk16(float a, float b) {
  fp16v2 p = __builtin_amdgcn_cvt_pkrtz(a, b);
  return __builtin_bit_cast(f16v2, p);
}

// fast tanh: 1 - 2/(e^{2v}+1), native exp/rcp (~1e-6 abs err, saturates correctly)
static __device__ __forceinline__ float fast_tanh(float v) {
  float e = __expf(2.0f * v);
  return 1.0f - 2.0f * __builtin_amdgcn_rcpf(e + 1.0f);
}

// Whl layout (f16, RTE): [ny(2)][kt(32)][ct(8)][lane(64)=khalf*32+c31][8 f16]
// One (ny,kt) slice = 8 KB contiguous -> staged linearly by global_load_lds.
// B-fragment ds_read is lds + lane*16 (+ct*1024): 64 lanes read 1024
// contiguous bytes -> zero bank conflicts (verified rounds 4/9/11).
__global__ __launch_bounds__(256) void k_convert_w(const float* __restrict__ W,
                                                   unsigned char* __restrict__ Whl) {
  int t = blockIdx.x * 256 + threadIdx.x;   // 32768 = 512 W-rows x 64 kgroups(8)
  int r512 = t >> 6, kg = t & 63;
  int ny = r512 >> 8, col = r512 & 255;
  int ct = col >> 5, c31 = col & 31;
  int kt = kg >> 1, khalf = kg & 1;
  const float* p = W + (size_t)r512 * DD + kg * 8;
  short8 h;
#pragma unroll
  for (int j = 0; j < 8; ++j) {
    _Float16 hh = (_Float16)p[j];              // RTE
    h[j] = (short)__builtin_bit_cast(unsigned short, hh);
  }
  unsigned char* dst = Whl + (size_t)ny * 262144 + (size_t)kt * 8192 +
                       ct * 1024 + (khalf * 32 + c31) * 16;
  *(short8*)dst = h;
}

// Fused GEMM(tanh-gate) + query-dot.  Wave = 64 rows x 128 cols (2 row-frags x
// 4 ct x 1 f16 MFMA, acc = 128 regs).  Block = 4 waves (2 rg x 2 cg) = 128
// rows x 256 cols (ny = col half).  A: HBM -> VGPR direct, double-buffered
// 2 kt ahead (no LDS round-trip).  B: gload_lds ring-3 (8 KB slices).
// Uniform pipeline: every kt issues [4 A-loads, 2 B-stages] -> WAITV(6)
// constant, no in-loop branches.  24.6 KB LDS, ~200 regs -> 2 blocks/CU.
__global__ __launch_bounds__(256, 2) void k_gemm_score(
    const float* __restrict__ x, const unsigned char* __restrict__ Whl,
    const float* __restrict__ bias, const float* __restrict__ query,
    float* __restrict__ score_part, int N) {
  __shared__ unsigned char ldsB[3][8192];
  __shared__ float comb[2][128];
  const int tid = threadIdx.x;
  const int wave = tid >> 6;
  const int lane = tid & 63;
  const int l31 = lane & 31;
  const int kh = lane >> 5;          // k-half within fragment
  const int rg = wave >> 1;          // row-group (0,1): rows rg*64..rg*64+63
  const int cg = wave & 1;           // col-group (0,1): cts cg*4..cg*4+3
  const int ny = blockIdx.x;
  const int brow0 = blockIdx.y * 128;

  const unsigned char* wsrc = Whl + (size_t)ny * 262144 +
                              (size_t)wave * 2048 + (size_t)lane * 16;
  // A: lane reads row rg*64 + f*32 + l31, k-window kt*16 + kh*8 .. +7 (two float4)
  const float* xp0 = x + (size_t)(brow0 + rg * 64 + l31) * DD + kh * 8;
  const float* xp1 = xp0 + (size_t)32 * DD;

  f32x16 acc[2][4];
#pragma unroll
  for (int f = 0; f < 2; ++f)
#pragma unroll
    for (int j = 0; j < 4; ++j)
#pragma unroll
      for (int r = 0; r < 16; ++r) acc[f][j][r] = 0.f;

#define ISSUE_A(BUF, KT)                                   \
  do {                                                     \
    const int km_ = (KT) & 31;                             \
    BUF[0] = *(const float4*)(xp0 + km_ * 16);             \
    BUF[1] = *(const float4*)(xp0 + km_ * 16 + 4);         \
    BUF[2] = *(const float4*)(xp1 + km_ * 16);             \
    BUF[3] = *(const float4*)(xp1 + km_ * 16 + 4);         \
  } while (0)

#define ISSUE_B(KT)                                                       \
  do {                                                                    \
    const int sl_ = (KT) % 3;                                             \
    const unsigned char* sb_ = wsrc + (size_t)((KT) & 31) * 8192;         \
    gload_lds16(sb_, &ldsB[sl_][wave * 2048]);                            \
    gload_lds16(sb_ + 1024, &ldsB[sl_][wave * 2048 + 1024]);              \
  } while (0)

  float4 aP[4], aQ[4];
  // prologue: 12 vmem in flight (A0,B0,A1,B1)
  ISSUE_A(aP, 0); ISSUE_B(0); MEMFENCE;
  ISSUE_A(aQ, 1); ISSUE_B(1); MEMFENCE;

#define BODY(KT, CUR)                                                     \
  do {                                                                    \
    WAITV(6);                          /* A(KT),B(KT) landed */           \
    __builtin_amdgcn_s_barrier();                                         \
    MEMFENCE;                                                             \
    /* consume A(KT) -> f16 frags, then reuse CUR for A(KT+2) */          \
    f16x8 ah0, ah1;                                                       \
    {                                                                     \
      f16v2 p_;                                                           \
      p_ = pk16(CUR[0].x, CUR[0].y); ah0[0] = p_[0]; ah0[1] = p_[1];      \
      p_ = pk16(CUR[0].z, CUR[0].w); ah0[2] = p_[0]; ah0[3] = p_[1];      \
      p_ = pk16(CUR[1].x, CUR[1].y); ah0[4] = p_[0]; ah0[5] = p_[1];      \
      p_ = pk16(CUR[1].z, CUR[1].w); ah0[6] = p_[0]; ah0[7] = p_[1];      \
      p_ = pk16(CUR[2].x, CUR[2].y); ah1[0] = p_[0]; ah1[1] = p_[1];      \
      p_ = pk16(CUR[2].z, CUR[2].w); ah1[2] = p_[0]; ah1[3] = p_[1];      \
      p_ = pk16(CUR[3].x, CUR[3].y); ah1[4] = p_[0]; ah1[5] = p_[1];      \
      p_ = pk16(CUR[3].z, CUR[3].w); ah1[6] = p_[0]; ah1[7] = p_[1];      \
    }                                                                     \
    MEMFENCE;                                                             \
    ISSUE_A(CUR, (KT) + 2);                                               \
    ISSUE_B((KT) + 2);                                                    \
    MEMFENCE;                                                             \
    const unsigned char* bb_ = &ldsB[(KT) % 3][lane * 16 + cg * 4096];    \
    __builtin_amdgcn_s_setprio(1);                                        \
    _Pragma("unroll")                                                     \
    for (int j = 0; j < 4; ++j) {                                         \
      f16x8 bh_ = *(const f16x8*)(bb_ + j * 1024);                        \
      acc[0][j] = __builtin_amdgcn_mfma_f32_32x32x16_f16(ah0, bh_, acc[0][j], 0, 0, 0); \
      acc[1][j] = __builtin_amdgcn_mfma_f32_32x32x16_f16(ah1, bh_, acc[1][j], 0, 0, 0); \
    }                                                                     \
    __builtin_amdgcn_s_setprio(0);                                        \
  } while (0)

#pragma unroll 1
  for (int it = 0; it < 16; ++it) {
    const int kt0 = it * 2;
    BODY(kt0, aP);
    BODY(kt0 + 1, aQ);
  }

  // epilogue: tanh + query-dot; reduce over the 32 col-lanes; combine cg halves
  float sp[2][16];
#pragma unroll
  for (int f = 0; f < 2; ++f)
#pragma unroll
    for (int r = 0; r < 16; ++r) sp[f][r] = 0.f;
#pragma unroll
  for (int j = 0; j < 4; ++j) {
    const int col = ny * 256 + (cg * 4 + j) * 32 + l31;
    const float bb2 = bias[col];
    const float qq = query[col];
#pragma unroll
    for (int f = 0; f < 2; ++f)
#pragma unroll
      for (int r = 0; r < 16; ++r)
        sp[f][r] += fast_tanh(acc[f][j][r] + bb2) * qq;
  }
  __syncthreads();
#pragma unroll
  for (int f = 0; f < 2; ++f)
#pragma unroll
    for (int r = 0; r < 16; ++r) {
      float v = sp[f][r];
      v += __shfl_xor(v, 1);
      v += __shfl_xor(v, 2);
      v += __shfl_xor(v, 4);
      v += __shfl_xor(v, 8);
      v += __shfl_xor(v, 16);
      if (l31 == 0)  // C row = (r&3) + 8*(r>>2) + 4*kh  (m74/m101 layout)
        comb[cg][rg * 64 + f * 32 + (r & 3) + 8 * (r >> 2) + 4 * kh] = v;
    }
  __syncthreads();
  if (tid < 128)
    score_part[(size_t)ny * N + brow0 + tid] = comb[0][tid] + comb[1][tid];
}

// Per-graph: segmented softmax over (sp0+sp1) + weighted sum of x rows -> out[g][512]
__global__ __launch_bounds__(256) void k_softmax_out(
    const float* __restrict__ x, const void* __restrict__ segp,
    const float* __restrict__ sp0, const float* __restrict__ sp1,
    float* __restrict__ out, int N) {
  const int g = blockIdx.x;
  const int tid = threadIdx.x;

  // dtype probe: int64 element N/2-1 is a graph id (<NG) iff buffer is int64.
  const long long probe = ((const long long*)segp)[N / 2 - 1];
  const bool is64 = ((unsigned long long)probe < (unsigned long long)NG);
  const long long* s64 = (const long long*)segp;
  const int* s32 = (const int*)segp;

  int s0, s1;
  {
    int lo = 0, hi = N;
    while (lo < hi) {
      int m = (lo + hi) >> 1;
      long long v = is64 ? s64[m] : (long long)s32[m];
      if (v < (long long)g) lo = m + 1; else hi = m;
    }
    s0 = lo;
    lo = s0; hi = N;
    while (lo < hi) {
      int m = (lo + hi) >> 1;
      long long v = is64 ? s64[m] : (long long)s32[m];
      if (v < (long long)(g + 1)) lo = m + 1; else hi = m;
    }
    s1 = lo;
  }

  __shared__ float red[4];
  __shared__ float wbuf[512];

  float lm = -INFINITY;
  for (int i = s0 + tid; i < s1; i += 256) lm = fmaxf(lm, sp0[i] + sp1[i]);
#pragma unroll
  for (int m = 1; m < 64; m <<= 1) lm = fmaxf(lm, __shfl_xor(lm, m));
  if ((tid & 63) == 0) red[tid >> 6] = lm;
  __syncthreads();
  const float mx = fmaxf(fmaxf(red[0], red[1]), fmaxf(red[2], red[3]));
  __syncthreads();

  float ls = 0.f;
  for (int i = s0 + tid; i < s1; i += 256) ls += expf(sp0[i] + sp1[i] - mx);
#pragma unroll
  for (int m = 1; m < 64; m <<= 1) ls += __shfl_xor(ls, m);
  if ((tid & 63) == 0) red[tid >> 6] = ls;
  __syncthreads();
  const float sum = red[0] + red[1] + red[2] + red[3];
  const float inv = sum > 0.f ? 1.0f / sum : 0.f;

  float a0 = 0.f, a1 = 0.f;
  const int c = tid * 2;
  for (int base = s0; base < s1; base += 512) {
    const int cnt = min(512, s1 - base);
    __syncthreads();
    for (int i = tid; i < cnt; i += 256)
      wbuf[i] = expf(sp0[base + i] + sp1[base + i] - mx) * inv;
    __syncthreads();
#pragma unroll 4
    for (int j = 0; j < cnt; ++j) {
      const float w = wbuf[j];
      const float2 xv = *(const float2*)(x + (size_t)(base + j) * DD + c);
      a0 = fmaf(w, xv.x, a0);
      a1 = fmaf(w, xv.y, a1);
    }
  }
  float* op = out + (size_t)g * DD + c;
  op[0] = a0;
  op[1] = a1;
}

extern "C" void kernel_launch(void* const* d_in, const int* in_sizes, int n_in,
                              void* d_out, int out_size, void* d_ws, size_t ws_size,
                              hipStream_t stream) {
  const float* x = (const float*)d_in[0];
  const void* seg = d_in[1];
  const float* W = (const float*)d_in[2];
  const float* b = (const float*)d_in[3];
  const float* q = (const float*)d_in[4];
  float* out = (float*)d_out;
  const int N = in_sizes[0] / DD;  // 131072

  unsigned char* Whl = (unsigned char*)d_ws;                 // 512 KB packed W (f16)
  float* sp0 = (float*)(Whl + 524288);                       // N partial scores (ny=0)
  float* sp1 = sp0 + N;                                      // N partial scores (ny=1)

  k_convert_w<<<128, 256, 0, stream>>>(W, Whl);
  dim3 grid(2, N / 128);                                     // x = ny fastest -> x-row cache reuse
  k_gemm_score<<<grid, 256, 0, stream>>>(x, Whl, b, q, sp0, N);
  k_softmax_out<<<NG, 256, 0, stream>>>(x, seg, sp0, sp1, out, N);
}

// Round 13
// 190.454 us; speedup vs baseline: 1.2236x; 1.2236x over previous
//
#include <hip/hip_runtime.h>

typedef _Float16 f16x8 __attribute__((ext_vector_type(8)));
typedef _Float16 f16x4 __attribute__((ext_vector_type(4)));
typedef __fp16 fp16v2 __attribute__((ext_vector_type(2)));
typedef _Float16 f16v2 __attribute__((ext_vector_type(2)));
typedef short short8 __attribute__((ext_vector_type(8)));
typedef float f32x16 __attribute__((ext_vector_type(16)));

#define DD 512
#define NG 512

typedef __attribute__((address_space(3))) void lds_void;
typedef __attribute__((address_space(1))) void glb_void;

static __device__ __forceinline__ void gload_lds16(const void* g, void* l) {
  __builtin_amdgcn_global_load_lds((const glb_void*)g, (lds_void*)l, 16, 0, 0);
}

#define MEMFENCE asm volatile("" ::: "memory")

// packed f32x2 -> f16x2 (RTZ), bit-cast to _Float16 vector
static __device__ __forceinline__ f16v2 pk16(float a, float b) {
  fp16v2 p = __builtin_amdgcn_cvt_pkrtz(a, b);
  return __builtin_bit_cast(f16v2, p);
}

// fast tanh: 1 - 2/(e^{2v}+1), native exp/rcp (~1e-6 abs err, saturates correctly)
static __device__ __forceinline__ float fast_tanh(float v) {
  float e = __expf(2.0f * v);
  return 1.0f - 2.0f * __builtin_amdgcn_rcpf(e + 1.0f);
}

// Whl layout (f16, RTE): [ny(2)][kt(32)][ct(8)][lane(64)=khalf*32+c31][8 f16]
// One (ny,kt) slice = 8 KB contiguous -> staged linearly by global_load_lds.
// B-fragment ds_read is lds + lane*16 (+ct*1024): 64 lanes read 1024
// contiguous bytes -> zero bank conflicts (verified rounds 4/9/11).
__global__ __launch_bounds__(256) void k_convert_w(const float* __restrict__ W,
                                                   unsigned char* __restrict__ Whl) {
  int t = blockIdx.x * 256 + threadIdx.x;   // 32768 = 512 W-rows x 64 kgroups(8)
  int r512 = t >> 6, kg = t & 63;
  int ny = r512 >> 8, col = r512 & 255;
  int ct = col >> 5, c31 = col & 31;
  int kt = kg >> 1, khalf = kg & 1;
  const float* p = W + (size_t)r512 * DD + kg * 8;
  short8 h;
#pragma unroll
  for (int j = 0; j < 8; ++j) {
    _Float16 hh = (_Float16)p[j];              // RTE
    h[j] = (short)__builtin_bit_cast(unsigned short, hh);
  }
  unsigned char* dst = Whl + (size_t)ny * 262144 + (size_t)kt * 8192 +
                       ct * 1024 + (khalf * 32 + c31) * 16;
  *(short8*)dst = h;
}

// Fused GEMM(tanh-gate) + query-dot.  R9 geometry: wave = 64 rows x 128 cols
// (2 row-frags x 4 ct x 1 f16 MFMA, acc = 128 AGPRs); block = 4 waves
// (2 rg x 2 cg) = 128 rows x 256 cols (ny = col half).
// NEW: A staged as f16 through registers: coalesced f32 loads (16x 64B
// segments/inst), pkrtz at stage time, linear ds_write_b64 into a 4 KB f16
// slice.  A LDS reads halve to 2 b128/wave/kt; no in-loop cvt VALU.
// Ring-3 A(4KB)+B(8KB), uniform s_waitcnt vmcnt(4) lgkmcnt(0) per body.
__global__ __launch_bounds__(256, 2) void k_gemm_score(
    const float* __restrict__ x, const unsigned char* __restrict__ Whl,
    const float* __restrict__ bias, const float* __restrict__ query,
    float* __restrict__ score_part, int N) {
  __shared__ unsigned char ldsB[3][8192];
  __shared__ unsigned char ldsA[3][4096];
  __shared__ float comb[2][128];
  const int tid = threadIdx.x;
  const int wave = tid >> 6;
  const int lane = tid & 63;
  const int l31 = lane & 31;
  const int kh = lane >> 5;          // k-half within fragment
  const int rg = wave >> 1;          // row-group (0,1): rows rg*64..rg*64+63
  const int cg = wave & 1;           // col-group (0,1): cts cg*4..cg*4+3
  const int ny = blockIdx.x;
  const int brow0 = blockIdx.y * 128;

  const unsigned char* wsrc = Whl + (size_t)ny * 262144 +
                              (size_t)wave * 2048 + (size_t)lane * 16;

  // A stage: wave w covers block rows w*32..w*32+31 of the kt window.
  // inst j (j=0,1): lane reads 16B f32 of row w*32 + j*16 + (lane>>2) at
  // k-offset (lane&3)*4 -> per inst 16 rows x 64B contiguous segments.
  const float* asrc = x + (size_t)(brow0 + wave * 32 + (lane >> 2)) * DD + (lane & 3) * 4;
  // f16 slice layout: [row(128)][8x f16(16B) per kh]: row*32 + koff
  const int wA = wave * 1024 + (lane >> 2) * 32 + (lane & 3) * 8;  // write byte addr
  const int rA0 = (rg * 64 + l31) * 32 + kh * 16;                  // frag read f=0
  const int rA1 = (rg * 64 + 32 + l31) * 32 + kh * 16;             // frag read f=1

  f32x16 acc[2][4];
#pragma unroll
  for (int f = 0; f < 2; ++f)
#pragma unroll
    for (int j = 0; j < 4; ++j)
#pragma unroll
      for (int r = 0; r < 16; ++r) acc[f][j][r] = 0.f;

#define AISSUE(BUF, KT)                                        \
  do {                                                         \
    const int km_ = (KT) & 31;                                 \
    BUF[0] = *(const float4*)(asrc + km_ * 16);                \
    BUF[1] = *(const float4*)(asrc + km_ * 16 + 16 * DD);      \
  } while (0)

#define BISSUE(KT)                                                        \
  do {                                                                    \
    const int sl_ = (KT) % 3;                                             \
    const unsigned char* sb_ = wsrc + (size_t)((KT) & 31) * 8192;         \
    gload_lds16(sb_, &ldsB[sl_][wave * 2048]);                            \
    gload_lds16(sb_ + 1024, &ldsB[sl_][wave * 2048 + 1024]);              \
  } while (0)

#define AWRITE(BUF, KT)                                                   \
  do {                                                                    \
    const int sl_ = (KT) % 3;                                             \
    f16v2 p0_ = pk16(BUF[0].x, BUF[0].y), p1_ = pk16(BUF[0].z, BUF[0].w); \
    f16v2 p2_ = pk16(BUF[1].x, BUF[1].y), p3_ = pk16(BUF[1].z, BUF[1].w); \
    f16x4 v0_ = {p0_[0], p0_[1], p1_[0], p1_[1]};                         \
    f16x4 v1_ = {p2_[0], p2_[1], p3_[0], p3_[1]};                         \
    *(f16x4*)(&ldsA[sl_][wA]) = v0_;                                      \
    *(f16x4*)(&ldsA[sl_][wA + 512]) = v1_;  /* +16 rows */                \
  } while (0)

  float4 bufP[2], bufQ[2];
  // prologue: A(0),A(1) direct (full drain, one-time), then fill the pipe in
  // FIFO order [A(2), B(0), A(3), B(1)] so body 0's vmcnt(4) drains A(2),B(0).
  AISSUE(bufP, 0); MEMFENCE;
  AISSUE(bufQ, 1); MEMFENCE;
  asm volatile("s_waitcnt vmcnt(0)" ::: "memory");
  AWRITE(bufP, 0);
  AWRITE(bufQ, 1);
  MEMFENCE;
  AISSUE(bufP, 2); MEMFENCE;
  BISSUE(0); MEMFENCE;
  AISSUE(bufQ, 3); MEMFENCE;
  BISSUE(1); MEMFENCE;

  // body kt: wait[A(kt+2),B(kt) landed] -> barrier -> write A(kt+2) (f16) ->
  // reissue buf <- A(kt+4) -> stage B(kt+2) -> compute kt.  Uniform for all kt
  // (tail indices masked &31; junk lands in dead slots).
#define BODY(KT, CUR)                                                     \
  do {                                                                    \
    asm volatile("s_waitcnt vmcnt(4) lgkmcnt(0)" ::: "memory");           \
    __builtin_amdgcn_s_barrier();                                         \
    MEMFENCE;                                                             \
    AWRITE(CUR, (KT) + 2);                                                \
    MEMFENCE;                                                             \
    AISSUE(CUR, (KT) + 4);                                                \
    MEMFENCE;                                                             \
    BISSUE((KT) + 2);                                                     \
    MEMFENCE;                                                             \
    const unsigned char* ab_ = &ldsA[(KT) % 3][0];                        \
    const unsigned char* bb_ = &ldsB[(KT) % 3][lane * 16 + cg * 4096];    \
    f16x8 a0_ = *(const f16x8*)(ab_ + rA0);                               \
    f16x8 a1_ = *(const f16x8*)(ab_ + rA1);                               \
    __builtin_amdgcn_s_setprio(1);                                        \
    _Pragma("unroll")                                                     \
    for (int j = 0; j < 4; ++j) {                                         \
      f16x8 bh_ = *(const f16x8*)(bb_ + j * 1024);                        \
      acc[0][j] = __builtin_amdgcn_mfma_f32_32x32x16_f16(a0_, bh_, acc[0][j], 0, 0, 0); \
      acc[1][j] = __builtin_amdgcn_mfma_f32_32x32x16_f16(a1_, bh_, acc[1][j], 0, 0, 0); \
    }                                                                     \
    __builtin_amdgcn_s_setprio(0);                                        \
  } while (0)

#pragma unroll 1
  for (int it = 0; it < 16; ++it) {
    BODY(it * 2, bufP);
    BODY(it * 2 + 1, bufQ);
  }

  // epilogue: tanh + query-dot; reduce over the 32 col-lanes; combine cg halves
  float sp[2][16];
#pragma unroll
  for (int f = 0; f < 2; ++f)
#pragma unroll
    for (int r = 0; r < 16; ++r) sp[f][r] = 0.f;
#pragma unroll
  for (int j = 0; j < 4; ++j) {
    const int col = ny * 256 + (cg * 4 + j) * 32 + l31;
    const float bb2 = bias[col];
    const float qq = query[col];
#pragma unroll
    for (int f = 0; f < 2; ++f)
#pragma unroll
      for (int r = 0; r < 16; ++r)
        sp[f][r] += fast_tanh(acc[f][j][r] + bb2) * qq;
  }
  __syncthreads();
#pragma unroll
  for (int f = 0; f < 2; ++f)
#pragma unroll
    for (int r = 0; r < 16; ++r) {
      float v = sp[f][r];
      v += __shfl_xor(v, 1);
      v += __shfl_xor(v, 2);
      v += __shfl_xor(v, 4);
      v += __shfl_xor(v, 8);
      v += __shfl_xor(v, 16);
      if (l31 == 0)  // C row = (r&3) + 8*(r>>2) + 4*kh  (m74/m101 layout)
        comb[cg][rg * 64 + f * 32 + (r & 3) + 8 * (r >> 2) + 4 * kh] = v;
    }
  __syncthreads();
  if (tid < 128)
    score_part[(size_t)ny * N + brow0 + tid] = comb[0][tid] + comb[1][tid];
}

// Per-graph: segmented softmax over (sp0+sp1) + weighted sum of x rows -> out[g][512]
__global__ __launch_bounds__(256) void k_softmax_out(
    const float* __restrict__ x, const void* __restrict__ segp,
    const float* __restrict__ sp0, const float* __restrict__ sp1,
    float* __restrict__ out, int N) {
  const int g = blockIdx.x;
  const int tid = threadIdx.x;

  // dtype probe: int64 element N/2-1 is a graph id (<NG) iff buffer is int64.
  const long long probe = ((const long long*)segp)[N / 2 - 1];
  const bool is64 = ((unsigned long long)probe < (unsigned long long)NG);
  const long long* s64 = (const long long*)segp;
  const int* s32 = (const int*)segp;

  int s0, s1;
  {
    int lo = 0, hi = N;
    while (lo < hi) {
      int m = (lo + hi) >> 1;
      long long v = is64 ? s64[m] : (long long)s32[m];
      if (v < (long long)g) lo = m + 1; else hi = m;
    }
    s0 = lo;
    lo = s0; hi = N;
    while (lo < hi) {
      int m = (lo + hi) >> 1;
      long long v = is64 ? s64[m] : (long long)s32[m];
      if (v < (long long)(g + 1)) lo = m + 1; else hi = m;
    }
    s1 = lo;
  }

  __shared__ float red[4];
  __shared__ float wbuf[512];

  float lm = -INFINITY;
  for (int i = s0 + tid; i < s1; i += 256) lm = fmaxf(lm, sp0[i] + sp1[i]);
#pragma unroll
  for (int m = 1; m < 64; m <<= 1) lm = fmaxf(lm, __shfl_xor(lm, m));
  if ((tid & 63) == 0) red[tid >> 6] = lm;
  __syncthreads();
  const float mx = fmaxf(fmaxf(red[0], red[1]), fmaxf(red[2], red[3]));
  __syncthreads();

  float ls = 0.f;
  for (int i = s0 + tid; i < s1; i += 256) ls += expf(sp0[i] + sp1[i] - mx);
#pragma unroll
  for (int m = 1; m < 64; m <<= 1) ls += __shfl_xor(ls, m);
  if ((tid & 63) == 0) red[tid >> 6] = ls;
  __syncthreads();
  const float sum = red[0] + red[1] + red[2] + red[3];
  const float inv = sum > 0.f ? 1.0f / sum : 0.f;

  float a0 = 0.f, a1 = 0.f;
  const int c = tid * 2;
  for (int base = s0; base < s1; base += 512) {
    const int cnt = min(512, s1 - base);
    __syncthreads();
    for (int i = tid; i < cnt; i += 256)
      wbuf[i] = expf(sp0[base + i] + sp1[base + i] - mx) * inv;
    __syncthreads();
#pragma unroll 4
    for (int j = 0; j < cnt; ++j) {
      const float w = wbuf[j];
      const float2 xv = *(const float2*)(x + (size_t)(base + j) * DD + c);
      a0 = fmaf(w, xv.x, a0);
      a1 = fmaf(w, xv.y, a1);
    }
  }
  float* op = out + (size_t)g * DD + c;
  op[0] = a0;
  op[1] = a1;
}

extern "C" void kernel_launch(void* const* d_in, const int* in_sizes, int n_in,
                              void* d_out, int out_size, void* d_ws, size_t ws_size,
                              hipStream_t stream) {
  const float* x = (const float*)d_in[0];
  const void* seg = d_in[1];
  const float* W = (const float*)d_in[2];
  const float* b = (const float*)d_in[3];
  const float* q = (const float*)d_in[4];
  float* out = (float*)d_out;
  const int N = in_sizes[0] / DD;  // 131072

  unsigned char* Whl = (unsigned char*)d_ws;                 // 512 KB packed W (f16)
  float* sp0 = (float*)(Whl + 524288);                       // N partial scores (ny=0)
  float* sp1 = sp0 + N;                                      // N partial scores (ny=1)

  k_convert_w<<<128, 256, 0, stream>>>(W, Whl);
  dim3 grid(2, N / 128);                                     // x = ny fastest -> x-row cache reuse
  k_gemm_score<<<grid, 256, 0, stream>>>(x, Whl, b, q, sp0, N);
  k_softmax_out<<<NG, 256, 0, stream>>>(x, seg, sp0, sp1, out, N);
}